// Round 1
// baseline (22.137 us; speedup 1.0000x reference)
//
#include <hip/hip_runtime.h>

#define SEQ_LEN 20
#define NUM_PED 64
#define NUM_SEQ 512
#define BATCH (NUM_SEQ * NUM_PED)   // 32768
#define MLP_DIM 1024
#define EPS 1e-5f

// ---------------------------------------------------------------------------
// Kernel 1: per-segment collision detection.
// One block per segment (512 blocks x 256 threads = 4 waves).
// Stage the segment's (20 timesteps x 64 peds x 2 floats) = 10KB into LDS.
// Wave w handles timesteps [5w, 5w+5); lane = pedestrian index.
// collision(ped) = exists (s, q): 0 < |pos_p - pos_q|^2 < 0.0625
// (bit-equivalent to reference's  masked-min(dist) < 0.25  in f32; verified
//  the sqrt rounding boundary: sqrt_rn(d2) < 0.25  <=>  d2 < 0.0625f)
// ---------------------------------------------------------------------------
__global__ __launch_bounds__(256) void collide_kernel(
    const float* __restrict__ traj,
    float* __restrict__ rewards,      // d_out + BATCH
    int* __restrict__ seg_counts) {   // per-segment count of rewards==1
  __shared__ float2 pos[SEQ_LEN * NUM_PED];      // 1280 float2 = 10 KB
  __shared__ unsigned long long colmask[4];

  const int g = blockIdx.x;
  const int t = threadIdx.x;

  // stage: 1280 float2, 5 per thread, coalesced (64 consecutive float2 per s)
  const float2* src = (const float2*)traj + (size_t)g * NUM_PED;
  #pragma unroll
  for (int k = 0; k < 5; ++k) {
    int idx = t + k * 256;
    int s = idx >> 6;          // / 64
    int inner = idx & 63;
    pos[idx] = src[(size_t)s * BATCH + inner];
  }
  __syncthreads();

  const int wave = t >> 6;
  const int lane = t & 63;
  const int sbase = wave * 5;

  // own positions for this wave's 5 timesteps
  float px[5], py[5];
  #pragma unroll
  for (int i = 0; i < 5; ++i) {
    float2 v = pos[(sbase + i) * NUM_PED + lane];
    px[i] = v.x; py[i] = v.y;
  }

  bool col = false;
  for (int q = 0; q < NUM_PED; ++q) {
    #pragma unroll
    for (int i = 0; i < 5; ++i) {
      // uniform LDS address across the wave -> broadcast, conflict-free
      float2 vq = pos[(sbase + i) * NUM_PED + q];
      float dx = __fsub_rn(px[i], vq.x);
      float dy = __fsub_rn(py[i], vq.y);
      float d2 = __fadd_rn(__fmul_rn(dx, dx), __fmul_rn(dy, dy));
      col = col || (d2 > 0.0f && d2 < 0.0625f);
    }
  }

  unsigned long long m = __ballot(col);
  if (lane == 0) colmask[wave] = m;
  __syncthreads();

  if (t < 64) {
    unsigned long long mm = colmask[0] | colmask[1] | colmask[2] | colmask[3];
    float reward = ((mm >> t) & 1ULL) ? 0.0f : 1.0f;   // 1 - collision
    rewards[g * NUM_PED + t] = reward;
    if (t == 0) seg_counts[g] = NUM_PED - __popcll(mm);
  }
}

// ---------------------------------------------------------------------------
// Kernel 2: classifier collapsed to closed form.
// Input column x in {0,1}; training-mode BatchNorm stats are closed-form in
// p = mean(x). Produces the two possible output scalars t0 (x=0), t1 (x=1).
// Single block, 1024 threads (one per MLP feature).
// ---------------------------------------------------------------------------
__device__ __forceinline__ float waveReduceSum(float v) {
  #pragma unroll
  for (int o = 32; o > 0; o >>= 1) v += __shfl_xor(v, o, 64);
  return v;
}

__global__ __launch_bounds__(1024) void classify_kernel(
    const int* __restrict__ seg_counts,
    const float* __restrict__ W1, const float* __restrict__ b1,
    const float* __restrict__ g1, const float* __restrict__ be1,
    const float* __restrict__ W2, const float* __restrict__ b2,
    const float* __restrict__ g2, const float* __restrict__ be2,
    float* __restrict__ tvals) {
  __shared__ float redA[16];
  __shared__ float redB[16];
  __shared__ float pshare;

  const int t = threadIdx.x;
  const int wave = t >> 6, lane = t & 63;

  // n1 = total count of rewards==1
  float c = (t < NUM_SEQ) ? (float)seg_counts[t] : 0.0f;
  c = waveReduceSum(c);
  if (lane == 0) redA[wave] = c;
  __syncthreads();
  if (t == 0) {
    float n1 = 0.0f;
    #pragma unroll
    for (int i = 0; i < 16; ++i) n1 += redA[i];
    pshare = n1 / (float)BATCH;
  }
  __syncthreads();
  const float p = pshare;

  // layer 1, feature t:
  //   h(x) = x*W1 + b1 ; mu = p*W1 + b1 ; var = p(1-p)*W1^2
  //   a(x) = relu(g1*(h-mu)*rsqrt(var+eps) + be1), h-mu = (x-p)*W1
  float w    = W1[t];
  float var1 = p * (1.0f - p) * w * w;
  float inv1 = rsqrtf(var1 + EPS);
  float gg = g1[t], bt = be1[t];
  float v0 = fmaxf(0.0f, gg * ((0.0f - p) * w) * inv1 + bt);
  float v1 = fmaxf(0.0f, gg * ((1.0f - p) * w) * inv1 + bt);

  // layer 2 pre-activation scalars s0, s1 (dot with W2)
  float w2 = W2[t];
  float e0 = waveReduceSum(v0 * w2);
  float e1 = waveReduceSum(v1 * w2);
  if (lane == 0) { redA[wave] = e0; redB[wave] = e1; }
  __syncthreads();
  if (t == 0) {
    float s0 = b2[0], s1 = b2[0];
    #pragma unroll
    for (int i = 0; i < 16; ++i) { s0 += redA[i]; s1 += redB[i]; }
    float mu   = p * s1 + (1.0f - p) * s0;
    float d    = s1 - s0;
    float var2 = p * (1.0f - p) * d * d;
    float inv2 = rsqrtf(var2 + EPS);
    float G = g2[0], BE = be2[0];
    tvals[0] = fmaxf(0.0f, G * (s0 - mu) * inv2 + BE);
    tvals[1] = fmaxf(0.0f, G * (s1 - mu) * inv2 + BE);
  }
}

// ---------------------------------------------------------------------------
// Kernel 3: scatter the two classifier scalars into scores.
// ---------------------------------------------------------------------------
__global__ __launch_bounds__(256) void score_kernel(
    const float* __restrict__ rewards, const float* __restrict__ tvals,
    float* __restrict__ scores) {
  const int b = blockIdx.x * 256 + threadIdx.x;
  const float t0 = tvals[0], t1 = tvals[1];
  scores[b] = (rewards[b] != 0.0f) ? t1 : t0;
}

extern "C" void kernel_launch(void* const* d_in, const int* in_sizes, int n_in,
                              void* d_out, int out_size, void* d_ws, size_t ws_size,
                              hipStream_t stream) {
  // setup_inputs order:
  // 0 traj, 1 traj_rel, 2 seq_start_end, 3 emb_W, 4 emb_b, 5 W_ih, 6 W_hh,
  // 7 b_ih, 8 b_hh, 9 W1, 10 b1, 11 g1, 12 be1, 13 W2, 14 b2, 15 g2, 16 be2
  const float* traj = (const float*)d_in[0];
  const float* W1  = (const float*)d_in[9];
  const float* b1  = (const float*)d_in[10];
  const float* g1  = (const float*)d_in[11];
  const float* be1 = (const float*)d_in[12];
  const float* W2  = (const float*)d_in[13];
  const float* b2  = (const float*)d_in[14];
  const float* g2  = (const float*)d_in[15];
  const float* be2 = (const float*)d_in[16];

  float* scores  = (float*)d_out;           // first BATCH elements
  float* rewards = scores + BATCH;          // second BATCH elements

  int*   seg_counts = (int*)d_ws;                                  // 512 ints
  float* tvals      = (float*)((char*)d_ws + NUM_SEQ * sizeof(int)); // 2 floats

  collide_kernel<<<NUM_SEQ, 256, 0, stream>>>(traj, rewards, seg_counts);
  classify_kernel<<<1, MLP_DIM, 0, stream>>>(seg_counts, W1, b1, g1, be1,
                                             W2, b2, g2, be2, tvals);
  score_kernel<<<BATCH / 256, 256, 0, stream>>>(rewards, tvals, scores);
}